// Round 9
// baseline (84.753 us; speedup 1.0000x reference)
//
#include <hip/hip_runtime.h>
#include <hip/hip_bf16.h>

// Problem sizes (fixed by the reference): B=2, T=512, D=768, U=768
#define BB 2
#define TT 512
#define DD 768
#define UU 768
#define NR (BB*TT)               // 1024 global rows
#define CC 2.8853900817779268f   // 2*log2(e): exp2(CC*z) = e^{2z}
#define HC 1.4426950408889634f   // CC/2:      exp2(HC*z) = e^{z} = sqrt(e^{2z})

typedef __attribute__((ext_vector_type(8))) short short8v;
typedef __attribute__((ext_vector_type(4))) float float4v;
typedef __attribute__((ext_vector_type(4))) unsigned short ushort4v;
typedef _Float16 half4v __attribute__((ext_vector_type(4)));

static __device__ __forceinline__ float fexp2(float x) { return __builtin_amdgcn_exp2f(x); }
static __device__ __forceinline__ float frcp(float x)  { return __builtin_amdgcn_rcpf(x); }
static __device__ __forceinline__ unsigned short bf16rn(float f) {
    unsigned u = __builtin_bit_cast(unsigned, f);
    u += 0x7FFFu + ((u >> 16) & 1u);
    return (unsigned short)(u >> 16);
}
static __device__ __forceinline__ float bf16tof(unsigned short h) {
    return __builtin_bit_cast(float, ((unsigned)h) << 16);
}

// ---------------------------------------------------------------------------
// Prep: split fp32 -> bf16 hi/lo.  z=0: W transpose+split -> WT[u][d];
// z=1: U likewise; z=2: x flat split (row-major kept).
// ---------------------------------------------------------------------------
__global__ __launch_bounds__(256) void prep_split(
    const float* __restrict__ x,
    const float* __restrict__ Wm,
    const float* __restrict__ Um,
    unsigned short* __restrict__ xhi, unsigned short* __restrict__ xlo,
    unsigned short* __restrict__ WThi, unsigned short* __restrict__ WTlo,
    unsigned short* __restrict__ UThi, unsigned short* __restrict__ UTlo)
{
    const int mode = blockIdx.z;
    const int t = threadIdx.x;

    if (mode == 2) {
        const int blk = blockIdx.y * 12 + blockIdx.x;       // 0..191
        const float4* src = (const float4*)x + (size_t)blk * 1024;
        #pragma unroll
        for (int i = 0; i < 4; ++i) {
            const int idx = i * 256 + t;
            const float4 v = src[idx];
            ushort4v h, l;
            h.x = bf16rn(v.x); l.x = bf16rn(v.x - bf16tof(h.x));
            h.y = bf16rn(v.y); l.y = bf16rn(v.y - bf16tof(h.y));
            h.z = bf16rn(v.z); l.z = bf16rn(v.z - bf16tof(h.z));
            h.w = bf16rn(v.w); l.w = bf16rn(v.w - bf16tof(h.w));
            const size_t off = (size_t)blk * 4096 + (size_t)idx * 4;
            *(ushort4v*)(xhi + off) = h;
            *(ushort4v*)(xlo + off) = l;
        }
        return;
    }
    if (blockIdx.y >= 12) return;                           // transpose grids are 12x12

    const float* __restrict__ S = (mode == 0) ? Wm : Um;    // [d][u]
    unsigned short* __restrict__ Thi = (mode == 0) ? WThi : UThi;
    unsigned short* __restrict__ Tlo = (mode == 0) ? WTlo : UTlo;

    __shared__ float tile[64][65];
    const int d0 = blockIdx.y * 64;
    const int u0 = blockIdx.x * 64;

    #pragma unroll
    for (int i = 0; i < 4; ++i) {
        const int f4 = i * 256 + t;
        const int r  = f4 >> 4;
        const int c4 = f4 & 15;
        const float4 v = *(const float4*)(S + (size_t)(d0 + r) * UU + u0 + c4 * 4);
        tile[r][c4 * 4 + 0] = v.x;
        tile[r][c4 * 4 + 1] = v.y;
        tile[r][c4 * 4 + 2] = v.z;
        tile[r][c4 * 4 + 3] = v.w;
    }
    __syncthreads();
    #pragma unroll
    for (int i = 0; i < 2; ++i) {
        const int cid = i * 256 + t;
        const int ur  = cid >> 3;
        const int kc  = cid & 7;
        short8v H, L;
        #pragma unroll
        for (int j = 0; j < 8; ++j) {
            const float f = tile[kc * 8 + j][ur];
            const unsigned short h = bf16rn(f);
            H[j] = (short)h;
            L[j] = (short)bf16rn(f - bf16tof(h));
        }
        const size_t off = (size_t)(u0 + ur) * DD + d0 + kc * 8;
        *(short8v*)(Thi + off) = H;
        *(short8v*)(Tlo + off) = L;
    }
}

// ---------------------------------------------------------------------------
// MFMA projection GEMM (bf16 3-term split).  A = WT/UT [u][k], B = x [r][k].
// 64x64 tile, BK=64, 4 waves (2x2), 16x16x32 bf16 MFMA, XOR-swizzled LDS.
//   mode 0: EW4[r>>2][u][r&3]          = exp2(CC * (x@W)[r][u])   (fp32)
//   mode 1: EUTH[b][u>>2][j][u&3]      = exp2(HC * ((x@U)[r][u] + bu[u]))
//           (fp16 sqrt-of-E; attn squares it)
// ---------------------------------------------------------------------------
__global__ __launch_bounds__(256) void gemm_mfma(
    const unsigned short* __restrict__ xhi, const unsigned short* __restrict__ xlo,
    const unsigned short* __restrict__ WThi, const unsigned short* __restrict__ WTlo,
    const unsigned short* __restrict__ UThi, const unsigned short* __restrict__ UTlo,
    const float* __restrict__ bu,
    float* __restrict__ EW4,
    _Float16* __restrict__ EUTH)
{
    const int mode = blockIdx.z;
    const unsigned short* __restrict__ Ahi = mode ? UThi : WThi;
    const unsigned short* __restrict__ Alo = mode ? UTlo : WTlo;

    __shared__ unsigned short lds[4 * 4096];   // [mat][row(64)][k(64)] swizzled

    const int tid  = threadIdx.x;
    const int lane = tid & 63;
    const int wid  = tid >> 6;
    const int wm   = wid >> 1, wn = wid & 1;
    const int u0   = blockIdx.y * 64;          // M tile (u), 12
    const int r0t  = blockIdx.x * 64;          // N tile (r), 16

    const int srow0 = tid >> 3;                // 0..31
    const int srow1 = srow0 + 32;
    const int sc0   = tid & 7;                 // k-chunk
    const int sw0   = (sc0 ^ (srow0 & 7)) << 3;

    short8v g0, g1, g2, g3, g4, g5, g6, g7;

#define LOADSTEP(K0) { \
    const size_t ka = (size_t)(K0) + sc0 * 8; \
    g0 = *(const short8v*)(Ahi + (size_t)(u0 + srow0) * DD + ka); \
    g1 = *(const short8v*)(Ahi + (size_t)(u0 + srow1) * DD + ka); \
    g2 = *(const short8v*)(Alo + (size_t)(u0 + srow0) * DD + ka); \
    g3 = *(const short8v*)(Alo + (size_t)(u0 + srow1) * DD + ka); \
    g4 = *(const short8v*)(xhi + (size_t)(r0t + srow0) * DD + ka); \
    g5 = *(const short8v*)(xhi + (size_t)(r0t + srow1) * DD + ka); \
    g6 = *(const short8v*)(xlo + (size_t)(r0t + srow0) * DD + ka); \
    g7 = *(const short8v*)(xlo + (size_t)(r0t + srow1) * DD + ka); }

#define WRITESTEP { \
    *(short8v*)&lds[0 * 4096 + srow0 * 64 + sw0] = g0; \
    *(short8v*)&lds[0 * 4096 + srow1 * 64 + sw0] = g1; \
    *(short8v*)&lds[1 * 4096 + srow0 * 64 + sw0] = g2; \
    *(short8v*)&lds[1 * 4096 + srow1 * 64 + sw0] = g3; \
    *(short8v*)&lds[2 * 4096 + srow0 * 64 + sw0] = g4; \
    *(short8v*)&lds[2 * 4096 + srow1 * 64 + sw0] = g5; \
    *(short8v*)&lds[3 * 4096 + srow0 * 64 + sw0] = g6; \
    *(short8v*)&lds[3 * 4096 + srow1 * 64 + sw0] = g7; }

    float4v acc[2][2] = {};

    LOADSTEP(0);
    for (int s = 0; s < 12; ++s) {
        __syncthreads();
        WRITESTEP;
        __syncthreads();
        if (s < 11) LOADSTEP((s + 1) * 64);

        short8v ah[2][2], al[2][2], bh[2][2], bl[2][2];
        #pragma unroll
        for (int f = 0; f < 2; ++f) {
            const int arow = wm * 32 + f * 16 + (lane & 15);
            const int brow = wn * 32 + f * 16 + (lane & 15);
            #pragma unroll
            for (int kk = 0; kk < 2; ++kk) {
                const int ck = kk * 4 + (lane >> 4);
                ah[f][kk] = *(const short8v*)&lds[0 * 4096 + arow * 64 + (((ck ^ (arow & 7))) << 3)];
                al[f][kk] = *(const short8v*)&lds[1 * 4096 + arow * 64 + (((ck ^ (arow & 7))) << 3)];
                bh[f][kk] = *(const short8v*)&lds[2 * 4096 + brow * 64 + (((ck ^ (brow & 7))) << 3)];
                bl[f][kk] = *(const short8v*)&lds[3 * 4096 + brow * 64 + (((ck ^ (brow & 7))) << 3)];
            }
        }
        #pragma unroll
        for (int kk = 0; kk < 2; ++kk)
            #pragma unroll
            for (int m = 0; m < 2; ++m)
                #pragma unroll
                for (int n = 0; n < 2; ++n) {
                    acc[m][n] = __builtin_amdgcn_mfma_f32_16x16x32_bf16(ah[m][kk], bh[n][kk], acc[m][n], 0, 0, 0);
                    acc[m][n] = __builtin_amdgcn_mfma_f32_16x16x32_bf16(ah[m][kk], bl[n][kk], acc[m][n], 0, 0, 0);
                    acc[m][n] = __builtin_amdgcn_mfma_f32_16x16x32_bf16(al[m][kk], bh[n][kk], acc[m][n], 0, 0, 0);
                }
    }

    // Epilogue. D-layout: col(r) = lane&15, row(u) = (lane>>4)*4 + reg.
    #pragma unroll
    for (int m = 0; m < 2; ++m) {
        #pragma unroll
        for (int n = 0; n < 2; ++n) {
            const int ub = u0 + wm * 32 + m * 16 + ((lane >> 4) << 2);
            const int r  = r0t + wn * 32 + n * 16 + (lane & 15);
            if (mode == 0) {
                float* dst = EW4 + ((size_t)(r >> 2) * UU + ub) * 4 + (r & 3);
                #pragma unroll
                for (int reg = 0; reg < 4; ++reg)
                    dst[reg * 4] = fexp2(acc[m][n][reg] * CC);
            } else {
                const int b = r >> 9, j = r & 511;
                const float4 bv = *(const float4*)(bu + ub);
                half4v o;
                o[0] = (_Float16)fexp2((acc[m][n][0] + bv.x) * HC);
                o[1] = (_Float16)fexp2((acc[m][n][1] + bv.y) * HC);
                o[2] = (_Float16)fexp2((acc[m][n][2] + bv.z) * HC);
                o[3] = (_Float16)fexp2((acc[m][n][3] + bv.w) * HC);
                *(half4v*)(EUTH + ((size_t)(b * 192 + (ub >> 2)) * 512 + j) * 4) = o;
            }
        }
    }
#undef LOADSTEP
#undef WRITESTEP
}

// ---------------------------------------------------------------------------
// Kernel B: fused e / softmax / PV.
// 256 blocks x 1024 threads (16 waves/CU = 4/SIMD); block owns 4 query rows.
// Thread = (j = tid&511, uh = tid>>9): each covers its u-half (384 u) of the
// e-sum; halves combined via LDS. EUTH is fp16 sqrt(E): one 8B load = 4 u.
// Pairwise-rcp per u-pair per row. PV: 16 waves x 32 j, at via LDS broadcast,
// 4-pass padded-stride LDS reduction.
// ---------------------------------------------------------------------------
__global__ __launch_bounds__(1024) void attn_fused(
    const float* __restrict__ x,
    const float* __restrict__ V_a,
    const float* __restrict__ EW4,
    const _Float16* __restrict__ EUTH,
    float* __restrict__ out)
{
    extern __shared__ float smem[];
    // float offsets (49424 B total):
    //   sw4  [0,3072)  vv [3072,3840)  xchg [4096,6144)  red [6144,6208)
    //   at4  [8192,10240)   part [0,12352) stride 772 (overlays; sequential)
    //   iv   [12352,12356)
    float4* sw4  = (float4*)smem;
    float*  vv   = smem + 3072;
    float*  xchg = smem + 4096;
    float*  red  = smem + 6144;
    float4* at4  = (float4*)(smem + 8192);
    float*  part = smem;
    float*  iv   = smem + 12352;

    const int tid  = threadIdx.x;
    const int lane = tid & 63;
    const int j    = tid & 511;
    const int uh   = tid >> 9;

    // XCD-bijective swizzle: 256 blocks = 8 XCDs x 32.
    const int bid = blockIdx.x;
    const int blk = (bid & 7) * 32 + (bid >> 3);

    const int r0 = blk * 4;
    const int b  = r0 >> 9;

    // ---- stage EW4 (block's 4 rows) + V into LDS ----
    if (tid < UU) {
        sw4[tid] = ((const float4*)EW4)[(size_t)blk * UU + tid];
        vv[tid]  = V_a[tid];
    }
    __syncthreads();

    // ---- e-loop over this thread's u-half ----
    const half4v* __restrict__ eqh =
        (const half4v*)EUTH + (size_t)(b * 192 + uh * 96) * 512 + j;

    float acc0 = 0.f, acc1 = 0.f, acc2 = 0.f, acc3 = 0.f;

#define PAIR(E0, E1, u0) { \
    const float4 S0 = sw4[(u0)]; \
    const float4 S1 = sw4[(u0) + 1]; \
    const float v0 = vv[(u0)], v1 = vv[(u0) + 1]; \
    { const float da = fmaf((E0), S0.x, 1.f), db = fmaf((E1), S1.x, 1.f); \
      float n = v0 * db; n = fmaf(v1, da, n); \
      acc0 = fmaf(n, frcp(da * db), acc0); } \
    { const float da = fmaf((E0), S0.y, 1.f), db = fmaf((E1), S1.y, 1.f); \
      float n = v0 * db; n = fmaf(v1, da, n); \
      acc1 = fmaf(n, frcp(da * db), acc1); } \
    { const float da = fmaf((E0), S0.z, 1.f), db = fmaf((E1), S1.z, 1.f); \
      float n = v0 * db; n = fmaf(v1, da, n); \
      acc2 = fmaf(n, frcp(da * db), acc2); } \
    { const float da = fmaf((E0), S0.w, 1.f), db = fmaf((E1), S1.w, 1.f); \
      float n = v0 * db; n = fmaf(v1, da, n); \
      acc3 = fmaf(n, frcp(da * db), acc3); } }
#define QUADH(H, UB) { \
    const float e0 = (float)(H)[0], e1 = (float)(H)[1]; \
    const float e2 = (float)(H)[2], e3 = (float)(H)[3]; \
    PAIR(e0 * e0, e1 * e1, (UB)); PAIR(e2 * e2, e3 * e3, (UB) + 2); }

    const int ubase = uh * 384 / 4;    // in u-quads? no: PAIR takes u index (not quad)
    // PAIR's u0 indexes sw4/vv by absolute u; quad q covers u = 4q..4q+3.
    const int ub0 = uh * 384;

    half4v c0 = eqh[0 * 512], c1 = eqh[1 * 512], c2 = eqh[2 * 512], c3 = eqh[3 * 512];
    #pragma unroll 1
    for (int c = 0; c < 23; ++c) {
        const int q = 4 * c;
        half4v n0 = eqh[(size_t)(q + 4) * 512];
        half4v n1 = eqh[(size_t)(q + 5) * 512];
        half4v n2 = eqh[(size_t)(q + 6) * 512];
        half4v n3 = eqh[(size_t)(q + 7) * 512];
        const int ub = ub0 + 16 * c;
        QUADH(c0, ub); QUADH(c1, ub + 4); QUADH(c2, ub + 8); QUADH(c3, ub + 12);
        c0 = n0; c1 = n1; c2 = n2; c3 = n3;
    }
    QUADH(c0, ub0 + 368); QUADH(c1, ub0 + 372); QUADH(c2, ub0 + 376); QUADH(c3, ub0 + 380);
    (void)ubase;

    // ---- combine u-halves ----
    if (uh) *(float4*)&xchg[j * 4] = make_float4(acc0, acc1, acc2, acc3);
    __syncthreads();
    if (!uh) {
        const float4 o = *(float4*)&xchg[j * 4];
        acc0 += o.x; acc1 += o.y; acc2 += o.z; acc3 += o.w;
    }

    // ---- softmax over j (waves 0..7 hold valid accs; barriers are uniform) ----
    float m0 = acc0, m1 = acc1, m2 = acc2, m3 = acc3;
    #pragma unroll
    for (int off = 32; off; off >>= 1) {
        m0 = fminf(m0, __shfl_xor(m0, off, 64));
        m1 = fminf(m1, __shfl_xor(m1, off, 64));
        m2 = fminf(m2, __shfl_xor(m2, off, 64));
        m3 = fminf(m3, __shfl_xor(m3, off, 64));
    }
    if (tid < 512 && lane == 0) {
        const int w = tid >> 6;
        red[0 * 8 + w] = m0; red[1 * 8 + w] = m1;
        red[2 * 8 + w] = m2; red[3 * 8 + w] = m3;
    }
    __syncthreads();
    float M0 = red[0], M1 = red[8], M2 = red[16], M3 = red[24];
    #pragma unroll
    for (int k = 1; k < 8; ++k) {
        M0 = fminf(M0, red[0 * 8 + k]);
        M1 = fminf(M1, red[1 * 8 + k]);
        M2 = fminf(M2, red[2 * 8 + k]);
        M3 = fminf(M3, red[3 * 8 + k]);
    }

    const float p0 = fexp2(CC * (M0 - acc0));
    const float p1 = fexp2(CC * (M1 - acc1));
    const float p2 = fexp2(CC * (M2 - acc2));
    const float p3 = fexp2(CC * (M3 - acc3));
    float s0 = p0, s1 = p1, s2 = p2, s3 = p3;
    #pragma unroll
    for (int off = 32; off; off >>= 1) {
        s0 += __shfl_xor(s0, off, 64);
        s1 += __shfl_xor(s1, off, 64);
        s2 += __shfl_xor(s2, off, 64);
        s3 += __shfl_xor(s3, off, 64);
    }
    __syncthreads();                      // red mins consumed
    if (tid < 512 && lane == 0) {
        const int w = tid >> 6;
        red[32 + 0 * 8 + w] = s0; red[32 + 1 * 8 + w] = s1;
        red[32 + 2 * 8 + w] = s2; red[32 + 3 * 8 + w] = s3;
    }
    __syncthreads();
    if (tid == 0) {
        float S0 = red[32], S1 = red[40], S2 = red[48], S3 = red[56];
        #pragma unroll
        for (int k = 1; k < 8; ++k) {
            S0 += red[32 + k]; S1 += red[40 + k];
            S2 += red[48 + k]; S3 += red[56 + k];
        }
        iv[0] = frcp(S0); iv[1] = frcp(S1); iv[2] = frcp(S2); iv[3] = frcp(S3);
    }
    if (tid < 512) at4[j] = make_float4(p0, p1, p2, p3);
    __syncthreads();

    // ---- PV: wave w (0..15) covers j in [32w, 32w+32); lane covers d=4*lane
    //      (+0, +256, +512). at broadcast from LDS. ----
    const int w16 = tid >> 6;
    const int jw  = w16 * 32;
    const float* __restrict__ xb = x + (size_t)b * TT * DD + (size_t)jw * DD + 4 * lane;
    float4 z4 = {0.f, 0.f, 0.f, 0.f};
    float4 pc00 = z4, pc01 = z4, pc02 = z4;
    float4 pc10 = z4, pc11 = z4, pc12 = z4;
    float4 pc20 = z4, pc21 = z4, pc22 = z4;
    float4 pc30 = z4, pc31 = z4, pc32 = z4;

#define F4(dst, a, xv) { dst.x = fmaf(a, xv.x, dst.x); dst.y = fmaf(a, xv.y, dst.y); \
                         dst.z = fmaf(a, xv.z, dst.z); dst.w = fmaf(a, xv.w, dst.w); }
    #pragma unroll 2
    for (int jj = 0; jj < 32; ++jj) {
        const float4 a = at4[jw + jj];
        const float* xr = xb + (size_t)jj * DD;
        const float4 x0 = *(const float4*)(xr);
        const float4 x1 = *(const float4*)(xr + 256);
        const float4 x2 = *(const float4*)(xr + 512);
        F4(pc00, a.x, x0); F4(pc01, a.x, x1); F4(pc02, a.x, x2);
        F4(pc10, a.y, x0); F4(pc11, a.y, x1); F4(pc12, a.y, x2);
        F4(pc20, a.z, x0); F4(pc21, a.z, x1); F4(pc22, a.z, x2);
        F4(pc30, a.w, x0); F4(pc31, a.w, x1); F4(pc32, a.w, x2);
    }
    __syncthreads();                      // at4 reads done before part overlay

#define REDPASS(PA, PB, PCc, R) { \
    *(float4*)&part[w16 * 772 + 4 * lane]       = PA; \
    *(float4*)&part[w16 * 772 + 256 + 4 * lane] = PB; \
    *(float4*)&part[w16 * 772 + 512 + 4 * lane] = PCc; \
    __syncthreads(); \
    if (tid < 768) { \
        float ssum = 0.f; \
        _Pragma("unroll") \
        for (int w2 = 0; w2 < 16; ++w2) ssum += part[w2 * 772 + tid]; \
        out[(size_t)(r0 + (R)) * DD + tid] = ssum * iv[(R)]; \
    } \
    __syncthreads(); }

    REDPASS(pc00, pc01, pc02, 0);
    REDPASS(pc10, pc11, pc12, 1);
    REDPASS(pc20, pc21, pc22, 2);
    REDPASS(pc30, pc31, pc32, 3);
}

// ---------------------------------------------------------------------------
extern "C" void kernel_launch(void* const* d_in, const int* in_sizes, int n_in,
                              void* d_out, int out_size, void* d_ws, size_t ws_size,
                              hipStream_t stream)
{
    const float* x   = (const float*)d_in[0];  // (B,T,D)
    const float* V_a = (const float*)d_in[1];  // (U,)
    const float* U_a = (const float*)d_in[2];  // (D,U)
    const float* b_u = (const float*)d_in[3];  // (U,)
    const float* W_a = (const float*)d_in[4];  // (D,U)
    float* out = (float*)d_out;                // (B,T,D)

    float* EW4 = (float*)d_ws;                             // [NR/4][UU][4] f32, 3 MB
    _Float16* EUTH = (_Float16*)(EW4 + (size_t)UU * NR);   // [B][192][512][4] f16, 1.5 MB
    unsigned short* xhi  = (unsigned short*)(EUTH + (size_t)BB * UU * TT);
    unsigned short* xlo  = xhi + (size_t)NR * DD;
    unsigned short* WThi = xlo + (size_t)NR * DD;
    unsigned short* WTlo = WThi + (size_t)UU * DD;
    unsigned short* UThi = WTlo + (size_t)UU * DD;
    unsigned short* UTlo = UThi + (size_t)UU * DD;

    hipLaunchKernelGGL(prep_split, dim3(12, 16, 3), dim3(256), 0, stream,
                       x, W_a, U_a, xhi, xlo, WThi, WTlo, UThi, UTlo);

    hipLaunchKernelGGL(gemm_mfma, dim3(16, 12, 2), dim3(256), 0, stream,
                       xhi, xlo, WThi, WTlo, UThi, UTlo, b_u, EW4, EUTH);

    const int ldsB = 12356 * sizeof(float);                // 49424 B
    hipLaunchKernelGGL(attn_fused, dim3(NR / 4), dim3(1024), ldsB, stream,
                       x, V_a, EW4, EUTH, out);
}

// Round 10
// 79.320 us; speedup vs baseline: 1.0685x; 1.0685x over previous
//
#include <hip/hip_runtime.h>
#include <hip/hip_bf16.h>

// Problem sizes (fixed by the reference): B=2, T=512, D=768, U=768
#define BB 2
#define TT 512
#define DD 768
#define UU 768
#define NR (BB*TT)               // 1024 global rows
#define CC 2.8853900817779268f   // 2*log2(e): exp2(CC*z) = e^{2z}

typedef __attribute__((ext_vector_type(8))) short short8v;
typedef __attribute__((ext_vector_type(4))) float float4v;
typedef __attribute__((ext_vector_type(4))) unsigned short ushort4v;

static __device__ __forceinline__ float fexp2(float x) { return __builtin_amdgcn_exp2f(x); }
static __device__ __forceinline__ float frcp(float x)  { return __builtin_amdgcn_rcpf(x); }
static __device__ __forceinline__ float readlane_f(float v, int l) {
    return __builtin_bit_cast(float, __builtin_amdgcn_readlane(__builtin_bit_cast(unsigned, v), l));
}
static __device__ __forceinline__ unsigned short bf16rn(float f) {
    unsigned u = __builtin_bit_cast(unsigned, f);
    u += 0x7FFFu + ((u >> 16) & 1u);
    return (unsigned short)(u >> 16);
}
static __device__ __forceinline__ float bf16tof(unsigned short h) {
    return __builtin_bit_cast(float, ((unsigned)h) << 16);
}

// ---------------------------------------------------------------------------
// Prep: split fp32 -> bf16 hi/lo.  z=0: W transpose+split -> WT[u][d];
// z=1: U likewise; z=2: x flat split (row-major kept).
// ---------------------------------------------------------------------------
__global__ __launch_bounds__(256) void prep_split(
    const float* __restrict__ x,
    const float* __restrict__ Wm,
    const float* __restrict__ Um,
    unsigned short* __restrict__ xhi, unsigned short* __restrict__ xlo,
    unsigned short* __restrict__ WThi, unsigned short* __restrict__ WTlo,
    unsigned short* __restrict__ UThi, unsigned short* __restrict__ UTlo)
{
    const int mode = blockIdx.z;
    const int t = threadIdx.x;

    if (mode == 2) {
        const int blk = blockIdx.y * 12 + blockIdx.x;       // 0..191
        const float4* src = (const float4*)x + (size_t)blk * 1024;
        #pragma unroll
        for (int i = 0; i < 4; ++i) {
            const int idx = i * 256 + t;
            const float4 v = src[idx];
            ushort4v h, l;
            h.x = bf16rn(v.x); l.x = bf16rn(v.x - bf16tof(h.x));
            h.y = bf16rn(v.y); l.y = bf16rn(v.y - bf16tof(h.y));
            h.z = bf16rn(v.z); l.z = bf16rn(v.z - bf16tof(h.z));
            h.w = bf16rn(v.w); l.w = bf16rn(v.w - bf16tof(h.w));
            const size_t off = (size_t)blk * 4096 + (size_t)idx * 4;
            *(ushort4v*)(xhi + off) = h;
            *(ushort4v*)(xlo + off) = l;
        }
        return;
    }
    if (blockIdx.y >= 12) return;                           // transpose grids are 12x12

    const float* __restrict__ S = (mode == 0) ? Wm : Um;    // [d][u]
    unsigned short* __restrict__ Thi = (mode == 0) ? WThi : UThi;
    unsigned short* __restrict__ Tlo = (mode == 0) ? WTlo : UTlo;

    __shared__ float tile[64][65];
    const int d0 = blockIdx.y * 64;
    const int u0 = blockIdx.x * 64;

    #pragma unroll
    for (int i = 0; i < 4; ++i) {
        const int f4 = i * 256 + t;
        const int r  = f4 >> 4;
        const int c4 = f4 & 15;
        const float4 v = *(const float4*)(S + (size_t)(d0 + r) * UU + u0 + c4 * 4);
        tile[r][c4 * 4 + 0] = v.x;
        tile[r][c4 * 4 + 1] = v.y;
        tile[r][c4 * 4 + 2] = v.z;
        tile[r][c4 * 4 + 3] = v.w;
    }
    __syncthreads();
    #pragma unroll
    for (int i = 0; i < 2; ++i) {
        const int cid = i * 256 + t;
        const int ur  = cid >> 3;
        const int kc  = cid & 7;
        short8v H, L;
        #pragma unroll
        for (int j = 0; j < 8; ++j) {
            const float f = tile[kc * 8 + j][ur];
            const unsigned short h = bf16rn(f);
            H[j] = (short)h;
            L[j] = (short)bf16rn(f - bf16tof(h));
        }
        const size_t off = (size_t)(u0 + ur) * DD + d0 + kc * 8;
        *(short8v*)(Thi + off) = H;
        *(short8v*)(Tlo + off) = L;
    }
}

// ---------------------------------------------------------------------------
// MFMA projection GEMM (bf16 3-term split).  A = WT/UT [u][k], B = x [r][k].
// 64x64 tile, BK=64, 4 waves (2x2), 16x16x32 bf16 MFMA, XOR-swizzled LDS.
//   mode 0: EW4[r>>2][u][r&3]     = exp2(CC * (x@W)[r][u])
//   mode 1: EUT[b][u>>2][j][u&3]  = exp2(CC * ((x@U)[r][u] + bu[u]))
// ---------------------------------------------------------------------------
__global__ __launch_bounds__(256) void gemm_mfma(
    const unsigned short* __restrict__ xhi, const unsigned short* __restrict__ xlo,
    const unsigned short* __restrict__ WThi, const unsigned short* __restrict__ WTlo,
    const unsigned short* __restrict__ UThi, const unsigned short* __restrict__ UTlo,
    const float* __restrict__ bu,
    float* __restrict__ EW4,
    float* __restrict__ EUT)
{
    const int mode = blockIdx.z;
    const unsigned short* __restrict__ Ahi = mode ? UThi : WThi;
    const unsigned short* __restrict__ Alo = mode ? UTlo : WTlo;

    __shared__ unsigned short lds[4 * 4096];   // [mat][row(64)][k(64)] swizzled

    const int tid  = threadIdx.x;
    const int lane = tid & 63;
    const int wid  = tid >> 6;
    const int wm   = wid >> 1, wn = wid & 1;
    const int u0   = blockIdx.y * 64;          // M tile (u), 12
    const int r0t  = blockIdx.x * 64;          // N tile (r), 16

    const int srow0 = tid >> 3;                // 0..31
    const int srow1 = srow0 + 32;
    const int sc0   = tid & 7;                 // k-chunk
    const int sw0   = (sc0 ^ (srow0 & 7)) << 3;

    short8v g0, g1, g2, g3, g4, g5, g6, g7;

#define LOADSTEP(K0) { \
    const size_t ka = (size_t)(K0) + sc0 * 8; \
    g0 = *(const short8v*)(Ahi + (size_t)(u0 + srow0) * DD + ka); \
    g1 = *(const short8v*)(Ahi + (size_t)(u0 + srow1) * DD + ka); \
    g2 = *(const short8v*)(Alo + (size_t)(u0 + srow0) * DD + ka); \
    g3 = *(const short8v*)(Alo + (size_t)(u0 + srow1) * DD + ka); \
    g4 = *(const short8v*)(xhi + (size_t)(r0t + srow0) * DD + ka); \
    g5 = *(const short8v*)(xhi + (size_t)(r0t + srow1) * DD + ka); \
    g6 = *(const short8v*)(xlo + (size_t)(r0t + srow0) * DD + ka); \
    g7 = *(const short8v*)(xlo + (size_t)(r0t + srow1) * DD + ka); }

#define WRITESTEP { \
    *(short8v*)&lds[0 * 4096 + srow0 * 64 + sw0] = g0; \
    *(short8v*)&lds[0 * 4096 + srow1 * 64 + sw0] = g1; \
    *(short8v*)&lds[1 * 4096 + srow0 * 64 + sw0] = g2; \
    *(short8v*)&lds[1 * 4096 + srow1 * 64 + sw0] = g3; \
    *(short8v*)&lds[2 * 4096 + srow0 * 64 + sw0] = g4; \
    *(short8v*)&lds[2 * 4096 + srow1 * 64 + sw0] = g5; \
    *(short8v*)&lds[3 * 4096 + srow0 * 64 + sw0] = g6; \
    *(short8v*)&lds[3 * 4096 + srow1 * 64 + sw0] = g7; }

    float4v acc[2][2] = {};

    LOADSTEP(0);
    for (int s = 0; s < 12; ++s) {
        __syncthreads();
        WRITESTEP;
        __syncthreads();
        if (s < 11) LOADSTEP((s + 1) * 64);

        short8v ah[2][2], al[2][2], bh[2][2], bl[2][2];
        #pragma unroll
        for (int f = 0; f < 2; ++f) {
            const int arow = wm * 32 + f * 16 + (lane & 15);
            const int brow = wn * 32 + f * 16 + (lane & 15);
            #pragma unroll
            for (int kk = 0; kk < 2; ++kk) {
                const int ck = kk * 4 + (lane >> 4);
                ah[f][kk] = *(const short8v*)&lds[0 * 4096 + arow * 64 + (((ck ^ (arow & 7))) << 3)];
                al[f][kk] = *(const short8v*)&lds[1 * 4096 + arow * 64 + (((ck ^ (arow & 7))) << 3)];
                bh[f][kk] = *(const short8v*)&lds[2 * 4096 + brow * 64 + (((ck ^ (brow & 7))) << 3)];
                bl[f][kk] = *(const short8v*)&lds[3 * 4096 + brow * 64 + (((ck ^ (brow & 7))) << 3)];
            }
        }
        #pragma unroll
        for (int kk = 0; kk < 2; ++kk)
            #pragma unroll
            for (int m = 0; m < 2; ++m)
                #pragma unroll
                for (int n = 0; n < 2; ++n) {
                    acc[m][n] = __builtin_amdgcn_mfma_f32_16x16x32_bf16(ah[m][kk], bh[n][kk], acc[m][n], 0, 0, 0);
                    acc[m][n] = __builtin_amdgcn_mfma_f32_16x16x32_bf16(ah[m][kk], bl[n][kk], acc[m][n], 0, 0, 0);
                    acc[m][n] = __builtin_amdgcn_mfma_f32_16x16x32_bf16(al[m][kk], bh[n][kk], acc[m][n], 0, 0, 0);
                }
    }

    // Epilogue. D-layout: col(r) = lane&15, row(u) = (lane>>4)*4 + reg.
    #pragma unroll
    for (int m = 0; m < 2; ++m) {
        #pragma unroll
        for (int n = 0; n < 2; ++n) {
            const int ub = u0 + wm * 32 + m * 16 + ((lane >> 4) << 2);
            const int r  = r0t + wn * 32 + n * 16 + (lane & 15);
            if (mode == 0) {
                float* dst = EW4 + ((size_t)(r >> 2) * UU + ub) * 4 + (r & 3);
                #pragma unroll
                for (int reg = 0; reg < 4; ++reg)
                    dst[reg * 4] = fexp2(acc[m][n][reg] * CC);
            } else {
                const int b = r >> 9, j = r & 511;
                const float4 bv = *(const float4*)(bu + ub);
                float4v o;
                o[0] = fexp2((acc[m][n][0] + bv.x) * CC);
                o[1] = fexp2((acc[m][n][1] + bv.y) * CC);
                o[2] = fexp2((acc[m][n][2] + bv.z) * CC);
                o[3] = fexp2((acc[m][n][3] + bv.w) * CC);
                *(float4v*)(EUT + (size_t)b * (UU * TT) + (size_t)(ub >> 2) * (TT * 4) + j * 4) = o;
            }
        }
    }
#undef LOADSTEP
#undef WRITESTEP
}

// ---------------------------------------------------------------------------
// Kernel B: fused e / softmax / PV.
// 256 blocks x 512 threads (1 block/CU); block owns 4 query rows; lane owns
// j = tid. STAGING folds V into the denominators: t[u][r] = s[u][r]/v[u],
// iv[u] = 1/v[u] (exact algebra: v/d = 1/(iv + E*t)). Per u-pair per row:
//   d0' = fma(E0,t0,iv0); d1' = fma(E1,t1,iv1);
//   acc += (d0'+d1') * rcp(d0'*d1')          [= v0/d0 + v1/d1]
// -> 5 VALU + 1 rcp per 2 products; 3 LDS reads (2xb128 + 1xb64) per pair.
// PV: wave w owns j in [64w,64w+64); at via readlane; 2-pass LDS reduction.
// ---------------------------------------------------------------------------
__global__ __launch_bounds__(512) void attn_fused(
    const float* __restrict__ x,
    const float* __restrict__ V_a,
    const float* __restrict__ EW4,
    const float* __restrict__ EUT,
    float* __restrict__ out)
{
    extern __shared__ float smem[];
    float*  part = smem;                       // [8][2][768] = 12288 (PV phase)
    float*  red  = smem;                       // 64 (softmax phase; aliases part)
    float4* tq   = (float4*)(smem + 12288);    // [768] {t0,t1,t2,t3}
    float*  ivh  = smem + 12288 + 3072;        // [768] iv (read as float2/pair)

    const int tid  = threadIdx.x;
    const int lane = tid & 63;
    const int w    = tid >> 6;

    // XCD-bijective swizzle: 256 blocks = 8 XCDs x 32.
    const int bid = blockIdx.x;
    const int blk = (bid & 7) * 32 + (bid >> 3);

    const int r0 = blk * 4;
    const int b  = r0 >> 9;

    // ---- stage t = s/v (float4 per u) + iv = 1/v into LDS ----
    {
        const float4* __restrict__ ew4q = (const float4*)EW4 + (size_t)blk * UU;
        for (int t = tid; t < UU; t += 512) {
            const float4 s4 = ew4q[t];
            const float rv = frcp(V_a[t]);
            tq[t]  = make_float4(s4.x * rv, s4.y * rv, s4.z * rv, s4.w * rv);
            ivh[t] = rv;
        }
    }
    __syncthreads();

    const float4*  __restrict__ eq  = (const float4*)(EUT + (size_t)b * UU * TT) + tid;
    const float2*  __restrict__ ivp = (const float2*)ivh;

    float acc0 = 0.f, acc1 = 0.f, acc2 = 0.f, acc3 = 0.f;

    // PAIR p covers u = 2p, 2p+1.
#define PAIR(E0, E1, p) { \
    const float4 T0 = tq[2 * (p)]; \
    const float4 T1 = tq[2 * (p) + 1]; \
    const float2 IV = ivp[(p)]; \
    { const float da = fmaf((E0), T0.x, IV.x), db = fmaf((E1), T1.x, IV.y); \
      acc0 = fmaf(da + db, frcp(da * db), acc0); } \
    { const float da = fmaf((E0), T0.y, IV.x), db = fmaf((E1), T1.y, IV.y); \
      acc1 = fmaf(da + db, frcp(da * db), acc1); } \
    { const float da = fmaf((E0), T0.z, IV.x), db = fmaf((E1), T1.z, IV.y); \
      acc2 = fmaf(da + db, frcp(da * db), acc2); } \
    { const float da = fmaf((E0), T0.w, IV.x), db = fmaf((E1), T1.w, IV.y); \
      acc3 = fmaf(da + db, frcp(da * db), acc3); } }
    // QUAD q covers u = 4q..4q+3 (pairs 2q, 2q+1).
#define QUAD(E4, q) { PAIR((E4).x, (E4).y, 2 * (q)); PAIR((E4).z, (E4).w, 2 * (q) + 1); }

    // chunk = 16 u = 4 quads; depth-1 register prefetch
    float4 c0 = eq[0 * 512], c1 = eq[1 * 512], c2 = eq[2 * 512], c3 = eq[3 * 512];
    #pragma unroll 1
    for (int c = 0; c < 47; ++c) {
        const int q = 4 * c;
        float4 n0_ = eq[(size_t)(q + 4) * 512];
        float4 n1_ = eq[(size_t)(q + 5) * 512];
        float4 n2_ = eq[(size_t)(q + 6) * 512];
        float4 n3_ = eq[(size_t)(q + 7) * 512];
        QUAD(c0, q); QUAD(c1, q + 1); QUAD(c2, q + 2); QUAD(c3, q + 3);
        c0 = n0_; c1 = n1_; c2 = n2_; c3 = n3_;
    }
    QUAD(c0, 188); QUAD(c1, 189); QUAD(c2, 190); QUAD(c3, 191);

    // ---- softmax over j (8-wave reduce); e-max <-> acc-min ----
    float m0 = acc0, m1 = acc1, m2 = acc2, m3 = acc3;
    #pragma unroll
    for (int off = 32; off; off >>= 1) {
        m0 = fminf(m0, __shfl_xor(m0, off, 64));
        m1 = fminf(m1, __shfl_xor(m1, off, 64));
        m2 = fminf(m2, __shfl_xor(m2, off, 64));
        m3 = fminf(m3, __shfl_xor(m3, off, 64));
    }
    if (lane == 0) {
        red[0 * 8 + w] = m0; red[1 * 8 + w] = m1;
        red[2 * 8 + w] = m2; red[3 * 8 + w] = m3;
    }
    __syncthreads();
    float M0 = red[0], M1 = red[8], M2 = red[16], M3 = red[24];
    #pragma unroll
    for (int k = 1; k < 8; ++k) {
        M0 = fminf(M0, red[0 * 8 + k]);
        M1 = fminf(M1, red[1 * 8 + k]);
        M2 = fminf(M2, red[2 * 8 + k]);
        M3 = fminf(M3, red[3 * 8 + k]);
    }

    const float p0 = fexp2(CC * (M0 - acc0));
    const float p1 = fexp2(CC * (M1 - acc1));
    const float p2 = fexp2(CC * (M2 - acc2));
    const float p3 = fexp2(CC * (M3 - acc3));
    float s0 = p0, s1 = p1, s2 = p2, s3 = p3;
    #pragma unroll
    for (int off = 32; off; off >>= 1) {
        s0 += __shfl_xor(s0, off, 64);
        s1 += __shfl_xor(s1, off, 64);
        s2 += __shfl_xor(s2, off, 64);
        s3 += __shfl_xor(s3, off, 64);
    }
    __syncthreads();                    // red reads done before rewrite
    if (lane == 0) {
        red[32 + 0 * 8 + w] = s0; red[32 + 1 * 8 + w] = s1;
        red[32 + 2 * 8 + w] = s2; red[32 + 3 * 8 + w] = s3;
    }
    __syncthreads();
    float S0 = red[32], S1 = red[40], S2 = red[48], S3 = red[56];
    #pragma unroll
    for (int k = 1; k < 8; ++k) {
        S0 += red[32 + k];
        S1 += red[40 + k];
        S2 += red[48 + k];
        S3 += red[56 + k];
    }
    const float i0 = frcp(S0), i1 = frcp(S1), i2 = frcp(S2), i3 = frcp(S3);

    // ---- PV (j-partition): wave w handles j in [64w, 64w+64) ----
    const float* __restrict__ xb = x + (size_t)b * TT * DD + (size_t)w * 64 * DD + 4 * lane;
    float4 z4 = {0.f, 0.f, 0.f, 0.f};
    float4 pc00 = z4, pc01 = z4, pc02 = z4;
    float4 pc10 = z4, pc11 = z4, pc12 = z4;
    float4 pc20 = z4, pc21 = z4, pc22 = z4;
    float4 pc30 = z4, pc31 = z4, pc32 = z4;

#define F4(dst, a, xv) { dst.x = fmaf(a, xv.x, dst.x); dst.y = fmaf(a, xv.y, dst.y); \
                         dst.z = fmaf(a, xv.z, dst.z); dst.w = fmaf(a, xv.w, dst.w); }
    #pragma unroll 2
    for (int jj = 0; jj < 64; ++jj) {
        const float a0 = readlane_f(p0, jj);
        const float a1 = readlane_f(p1, jj);
        const float a2 = readlane_f(p2, jj);
        const float a3 = readlane_f(p3, jj);
        const float* xr = xb + (size_t)jj * DD;
        const float4 x0 = *(const float4*)(xr);
        const float4 x1 = *(const float4*)(xr + 256);
        const float4 x2 = *(const float4*)(xr + 512);
        F4(pc00, a0, x0); F4(pc01, a0, x1); F4(pc02, a0, x2);
        F4(pc10, a1, x0); F4(pc11, a1, x1); F4(pc12, a1, x2);
        F4(pc20, a2, x0); F4(pc21, a2, x1); F4(pc22, a2, x2);
        F4(pc30, a3, x0); F4(pc31, a3, x1); F4(pc32, a3, x2);
    }

    __syncthreads();                    // softmax reds done before part reuse
    {
        float* pw = part + w * 1536 + 4 * lane;
        *(float4*)(pw + 0)    = pc00;
        *(float4*)(pw + 256)  = pc01;
        *(float4*)(pw + 512)  = pc02;
        *(float4*)(pw + 768)  = pc10;
        *(float4*)(pw + 1024) = pc11;
        *(float4*)(pw + 1280) = pc12;
    }
    __syncthreads();
    #pragma unroll
    for (int e = 0; e < 3; ++e) {
        const int idx = e * 512 + tid;          // 0..1535
        const int r   = (idx >= 768) ? 1 : 0;
        const int d   = idx - r * 768;
        float ssum = 0.f;
        #pragma unroll
        for (int w2 = 0; w2 < 8; ++w2) ssum += part[w2 * 1536 + r * 768 + d];
        out[(size_t)(r0 + r) * DD + d] = ssum * (r ? i1 : i0);
    }
    __syncthreads();
    {
        float* pw = part + w * 1536 + 4 * lane;
        *(float4*)(pw + 0)    = pc20;
        *(float4*)(pw + 256)  = pc21;
        *(float4*)(pw + 512)  = pc22;
        *(float4*)(pw + 768)  = pc30;
        *(float4*)(pw + 1024) = pc31;
        *(float4*)(pw + 1280) = pc32;
    }
    __syncthreads();
    #pragma unroll
    for (int e = 0; e < 3; ++e) {
        const int idx = e * 512 + tid;
        const int r   = (idx >= 768) ? 1 : 0;
        const int d   = idx - r * 768;
        float ssum = 0.f;
        #pragma unroll
        for (int w2 = 0; w2 < 8; ++w2) ssum += part[w2 * 1536 + r * 768 + d];
        out[(size_t)(r0 + 2 + r) * DD + d] = ssum * (r ? i3 : i2);
    }
}

// ---------------------------------------------------------------------------
extern "C" void kernel_launch(void* const* d_in, const int* in_sizes, int n_in,
                              void* d_out, int out_size, void* d_ws, size_t ws_size,
                              hipStream_t stream)
{
    const float* x   = (const float*)d_in[0];  // (B,T,D)
    const float* V_a = (const float*)d_in[1];  // (U,)
    const float* U_a = (const float*)d_in[2];  // (D,U)
    const float* b_u = (const float*)d_in[3];  // (U,)
    const float* W_a = (const float*)d_in[4];  // (D,U)
    float* out = (float*)d_out;                // (B,T,D)

    float* EW4 = (float*)d_ws;                             // [NR/4][UU][4] f32, 3 MB
    float* EUT = EW4 + (size_t)UU * NR;                    // [B][U/4][T][4] f32, 3 MB
    unsigned short* xhi  = (unsigned short*)(EUT + (size_t)BB * UU * TT);
    unsigned short* xlo  = xhi + (size_t)NR * DD;
    unsigned short* WThi = xlo + (size_t)NR * DD;
    unsigned short* WTlo = WThi + (size_t)UU * DD;
    unsigned short* UThi = WTlo + (size_t)UU * DD;
    unsigned short* UTlo = UThi + (size_t)UU * DD;

    hipLaunchKernelGGL(prep_split, dim3(12, 16, 3), dim3(256), 0, stream,
                       x, W_a, U_a, xhi, xlo, WThi, WTlo, UThi, UTlo);

    hipLaunchKernelGGL(gemm_mfma, dim3(16, 12, 2), dim3(256), 0, stream,
                       xhi, xlo, WThi, WTlo, UThi, UTlo, b_u, EW4, EUT);

    const int ldsB = (12288 + 3072 + 768) * sizeof(float); // 64512 B
    hipLaunchKernelGGL(attn_fused, dim3(NR / 4), dim3(512), ldsB, stream,
                       x, V_a, EW4, EUT, out);
}